// Round 13
// baseline (827.389 us; speedup 1.0000x reference)
//
#include <hip/hip_runtime.h>

#define VV 4
#define NN 4096
#define HH 128
#define CAP 64
#define GR 32            // rows per block in gemm2c
#define CHP (NN / GR)    // 128 column-sum partial chunks per view

typedef __attribute__((ext_vector_type(4))) float fvec4;   // nontemporal-loadable

// ---------------------------------------------------------------------------
// Kernel 1: scan dense adjacency -> per-row neighbor lists + dinv.
// ---------------------------------------------------------------------------
__global__ __launch_bounds__(256) void k_build_csr(
    const float* __restrict__ adjs, int* __restrict__ nbr,
    int* __restrict__ cnt, float* __restrict__ dinv)
{
    int wave = threadIdx.x >> 6;
    int lane = threadIdx.x & 63;
    int r = blockIdx.x * 4 + wave;              // global row in [0, V*N)
    const fvec4* row = (const fvec4*)(adjs + (size_t)r * NN);
    int* out = nbr + (size_t)r * CAP;
    unsigned long long lm = (1ull << lane) - 1ull;
    int base = 0;
    #pragma unroll 4
    for (int c = 0; c < NN / 256; ++c) {
        fvec4 x = __builtin_nontemporal_load(&row[c * 64 + lane]);
        int c0 = (x.x != 0.f), c1 = (x.y != 0.f), c2 = (x.z != 0.f), c3 = (x.w != 0.f);
        unsigned long long b0 = __ballot(c0), b1 = __ballot(c1);
        unsigned long long b2 = __ballot(c2), b3 = __ballot(c3);
        int pos = base + __popcll(b0 & lm) + __popcll(b1 & lm)
                       + __popcll(b2 & lm) + __popcll(b3 & lm);
        int e = c * 256 + lane * 4;
        if (c0 && pos < CAP) out[pos] = e;     pos += c0;
        if (c1 && pos < CAP) out[pos] = e + 1; pos += c1;
        if (c2 && pos < CAP) out[pos] = e + 2; pos += c2;
        if (c3 && pos < CAP) out[pos] = e + 3; pos += c3;
        base += __popcll(b0) + __popcll(b1) + __popcll(b2) + __popcll(b3);
    }
    if (lane == 0) {
        cnt[r]  = base < CAP ? base : CAP;
        dinv[r] = rsqrtf((float)(base + 1));   // +1 self loop
    }
}

// ---------------------------------------------------------------------------
// Kernel 2: h1 = relu(A_norm @ w1 + b1). 4 rows per 512-thread block.
// (measured 4.1 us)
// ---------------------------------------------------------------------------
__global__ __launch_bounds__(512) void k_spmm1(
    const float* __restrict__ w1, const float* __restrict__ b1,
    const int* __restrict__ nbr, const int* __restrict__ cnt,
    const float* __restrict__ dinv, float* __restrict__ h1)
{
    int xcd  = blockIdx.x & 7;
    int slot = blockIdx.x >> 3;
    int wid  = (xcd >> 1) * 1024 + slot * 2 + (xcd & 1);
    int g = threadIdx.x >> 7;
    int h = threadIdx.x & 127;
    int r = wid * 4 + g;
    int v = r >> 12;
    __shared__ int   s_j[4][CAP];
    __shared__ float s_w[4][CAP];
    int n = cnt[r];
    float dr = dinv[r];
    if (h < n) {
        int j = nbr[(size_t)r * CAP + h];
        s_j[g][h] = j;
        s_w[g][h] = dinv[v * NN + j];
    }
    __syncthreads();
    float acc = dr * w1[(size_t)r * HH + h];
    #pragma unroll 4
    for (int k = 0; k < n; ++k)
        acc += s_w[g][k] * w1[((size_t)(v * NN + s_j[g][k])) * HH + h];
    float val = dr * acc + b1[v * HH + h];
    h1[(size_t)r * HH + h] = val > 0.f ? val : 0.f;
}

// ---------------------------------------------------------------------------
// Kernel 3a: u = A_norm @ h1 (gather only).
// ---------------------------------------------------------------------------
__global__ __launch_bounds__(512) void k_gather2(
    const float* __restrict__ h1, const int* __restrict__ nbr,
    const int* __restrict__ cnt, const float* __restrict__ dinv,
    float* __restrict__ u)
{
    int xcd  = blockIdx.x & 7;
    int slot = blockIdx.x >> 3;
    int wid  = (xcd >> 1) * 1024 + slot * 2 + (xcd & 1);
    int g = threadIdx.x >> 7;
    int h = threadIdx.x & 127;
    int r = wid * 4 + g;
    int v = r >> 12;
    __shared__ int   s_j[4][CAP];
    __shared__ float s_w[4][CAP];
    int n = cnt[r];
    float dr = dinv[r];
    if (h < n) {
        int j = nbr[(size_t)r * CAP + h];
        s_j[g][h] = j;
        s_w[g][h] = dinv[v * NN + j];
    }
    __syncthreads();
    float acc = dr * h1[(size_t)r * HH + h];
    #pragma unroll 4
    for (int k = 0; k < n; ++k)
        acc += s_w[g][k] * h1[((size_t)(v * NN + s_j[g][k])) * HH + h];
    u[(size_t)r * HH + h] = dr * acc;
}

// ---------------------------------------------------------------------------
// Kernel 3b: h2 = relu(u @ w2 + b2) + per-block column partial sums.
// ---------------------------------------------------------------------------
__global__ __launch_bounds__(256) void k_gemm2c(
    const float* __restrict__ u, const float* __restrict__ w2,
    const float* __restrict__ b2, float* __restrict__ h2,
    float* __restrict__ part)
{
    const int bpv = NN / GR;            // 128
    int v = blockIdx.x / bpv;
    int rbase_g = blockIdx.x * GR;      // first global row
    __shared__ float s_u[GR][HH];       // 16 KB
    __shared__ float s_p[8][HH];        // 4 KB
    const float4* src = (const float4*)(u + (size_t)rbase_g * HH);
    for (int idx = threadIdx.x; idx < GR * HH / 4; idx += 256)
        ((float4*)s_u)[idx] = src[idx];
    __syncthreads();

    int r0 = (threadIdx.x >> 5) * 4;          // 0..28
    int c0 = (threadIdx.x & 31) * 4;          // 0..124
    const float* wv = w2 + (size_t)v * HH * HH;
    float acc[4][4];
    #pragma unroll
    for (int i = 0; i < 4; ++i)
        #pragma unroll
        for (int j = 0; j < 4; ++j) acc[i][j] = 0.f;
    for (int k = 0; k < HH; k += 4) {
        float4 a[4], w[4];
        #pragma unroll
        for (int i = 0; i < 4; ++i) a[i] = *(const float4*)&s_u[r0 + i][k];
        #pragma unroll
        for (int kk = 0; kk < 4; ++kk) w[kk] = *(const float4*)&wv[(size_t)(k + kk) * HH + c0];
        #pragma unroll
        for (int i = 0; i < 4; ++i)
            #pragma unroll
            for (int j = 0; j < 4; ++j) {
                acc[i][j] += a[i].x * ((const float*)&w[0])[j];
                acc[i][j] += a[i].y * ((const float*)&w[1])[j];
                acc[i][j] += a[i].z * ((const float*)&w[2])[j];
                acc[i][j] += a[i].w * ((const float*)&w[3])[j];
            }
    }
    float p[4];
    #pragma unroll
    for (int j = 0; j < 4; ++j) {
        float b = b2[v * HH + c0 + j];
        float s = 0.f;
        #pragma unroll
        for (int i = 0; i < 4; ++i) {
            float val = acc[i][j] + b;
            val = val > 0.f ? val : 0.f;
            acc[i][j] = val;
            s += val;
        }
        p[j] = s;
    }
    float* dst = h2 + (size_t)rbase_g * HH;
    #pragma unroll
    for (int i = 0; i < 4; ++i) {
        float4 o = { acc[i][0], acc[i][1], acc[i][2], acc[i][3] };
        *(float4*)&dst[(size_t)(r0 + i) * HH + c0] = o;
    }
    *(float4*)&s_p[threadIdx.x >> 5][c0] = *(float4*)p;
    __syncthreads();
    if (threadIdx.x < HH) {
        float a = 0.f;
        #pragma unroll
        for (int q = 0; q < 8; ++q) a += s_p[q][threadIdx.x];
        part[(size_t)blockIdx.x * HH + threadIdx.x] = a;
    }
}

// ---------------------------------------------------------------------------
// Kernel 4: finish summaries, attention MLP, softmax. Single block (512 thr).
// ---------------------------------------------------------------------------
__global__ __launch_bounds__(512) void k_attn(
    const float* __restrict__ part, const float* __restrict__ wa1,
    const float* __restrict__ ba1, const float* __restrict__ wa2,
    const float* __restrict__ ba2, float* __restrict__ attn_out,
    float* __restrict__ attn_ws)
{
    __shared__ float s_sum[VV * HH];
    __shared__ float s_red[256];
    __shared__ float s_score[VV];
    {
        int v = threadIdx.x >> 7, h = threadIdx.x & 127;
        float a = 0.f;
        #pragma unroll 8
        for (int c = 0; c < CHP; ++c) a += part[(size_t)(v * CHP + c) * HH + h];
        s_sum[v * HH + h] = a * (1.0f / NN);
    }
    __syncthreads();
    if (threadIdx.x < 256) {
        int v = threadIdx.x >> 6, u = threadIdx.x & 63;
        float a = ba1[u];
        for (int k = 0; k < HH; ++k) a += s_sum[v * HH + k] * wa1[k * 64 + u];
        s_red[threadIdx.x] = tanhf(a) * wa2[u];
    }
    __syncthreads();
    if (threadIdx.x < VV) {
        float sc = ba2[0];
        for (int uu = 0; uu < 64; ++uu) sc += s_red[threadIdx.x * 64 + uu];
        s_score[threadIdx.x] = sc;
    }
    __syncthreads();
    if (threadIdx.x == 0) {
        float m = s_score[0];
        for (int i = 1; i < VV; ++i) m = fmaxf(m, s_score[i]);
        float e[VV], den = 0.f;
        for (int i = 0; i < VV; ++i) { e[i] = __expf(s_score[i] - m); den += e[i]; }
        for (int i = 0; i < VV; ++i) {
            float av = e[i] / den;
            attn_out[i] = av;
            attn_ws[i]  = av;
        }
    }
}

// ---------------------------------------------------------------------------
// Kernel 5: fusion MLP v2 (measured 27.4 us) — FR=16, grid 256.
// ---------------------------------------------------------------------------
#define F2 16
#define S1 516
#define S2 260
#define S3 132
__global__ __launch_bounds__(512) void k_fusion2(
    const float* __restrict__ h2, const float* __restrict__ attn_ws,
    const float* __restrict__ wf1, const float* __restrict__ bf1,
    const float* __restrict__ wf2, const float* __restrict__ bf2,
    float* __restrict__ fused)
{
    __shared__ float s_in[F2][S1];
    __shared__ float s_hid[F2][S2];
    float (*s_part)[S2] = (float (*)[S2])&s_in[0][0];
    float (*s_p2)[S3]   = (float (*)[S3])&s_in[0][0];

    int nbase = blockIdx.x * F2;
    int wv   = threadIdx.x >> 6;
    int lane = threadIdx.x & 63;
    float at[VV];
    #pragma unroll
    for (int v = 0; v < VV; ++v) at[v] = attn_ws[v];

    for (int idx = threadIdx.x; idx < F2 * 128; idx += 512) {
        int r  = idx >> 7;
        int c4 = idx & 127;
        int v  = c4 >> 5;
        int h4 = c4 & 31;
        const float4* srcr = (const float4*)(h2 + ((size_t)v * NN + nbase + r) * HH);
        float4 x = srcr[h4];
        float s = at[v];
        x.x *= s; x.y *= s; x.z *= s; x.w *= s;
        *(float4*)&s_in[r][c4 * 4] = x;
    }
    __syncthreads();

    int cg = wv & 3, kh = wv >> 2;
    int ccol  = cg * 64 + (lane & 15) * 4;
    int rbase = (lane >> 4) * 4;
    float acc[4][4];
    #pragma unroll
    for (int i = 0; i < 4; ++i)
        #pragma unroll
        for (int j = 0; j < 4; ++j) acc[i][j] = 0.f;
    {
        int k0 = kh * 256;
        const float* wrow = wf1 + (size_t)k0 * 256 + ccol;
        #pragma unroll 4
        for (int k = 0; k < 256; ++k) {
            float4 wk = *(const float4*)wrow;
            wrow += 256;
            float a0 = s_in[rbase + 0][k0 + k];
            float a1 = s_in[rbase + 1][k0 + k];
            float a2 = s_in[rbase + 2][k0 + k];
            float a3 = s_in[rbase + 3][k0 + k];
            acc[0][0] += a0 * wk.x; acc[0][1] += a0 * wk.y; acc[0][2] += a0 * wk.z; acc[0][3] += a0 * wk.w;
            acc[1][0] += a1 * wk.x; acc[1][1] += a1 * wk.y; acc[1][2] += a1 * wk.z; acc[1][3] += a1 * wk.w;
            acc[2][0] += a2 * wk.x; acc[2][1] += a2 * wk.y; acc[2][2] += a2 * wk.z; acc[2][3] += a2 * wk.w;
            acc[3][0] += a3 * wk.x; acc[3][1] += a3 * wk.y; acc[3][2] += a3 * wk.z; acc[3][3] += a3 * wk.w;
        }
    }
    __syncthreads();
    if (kh == 1) {
        #pragma unroll
        for (int i = 0; i < 4; ++i)
            *(float4*)&s_part[rbase + i][ccol] = *(float4*)&acc[i][0];
    }
    __syncthreads();
    if (kh == 0) {
        float4 b = *(const float4*)&bf1[ccol];
        #pragma unroll
        for (int i = 0; i < 4; ++i) {
            float4 p = *(float4*)&s_part[rbase + i][ccol];
            float h0  = acc[i][0] + p.x + b.x;
            float h1v = acc[i][1] + p.y + b.y;
            float h2v = acc[i][2] + p.z + b.z;
            float h3  = acc[i][3] + p.w + b.w;
            float4 o;
            o.x = h0  > 0.f ? h0  : 0.f;
            o.y = h1v > 0.f ? h1v : 0.f;
            o.z = h2v > 0.f ? h2v : 0.f;
            o.w = h3  > 0.f ? h3  : 0.f;
            *(float4*)&s_hid[rbase + i][ccol] = o;
        }
    }
    __syncthreads();

    int c2 = cg * 32 + (lane & 15) * 2;
    float acc2[4][2];
    #pragma unroll
    for (int i = 0; i < 4; ++i) { acc2[i][0] = 0.f; acc2[i][1] = 0.f; }
    {
        int k0 = kh * 128;
        const float* wrow = wf2 + (size_t)k0 * 128 + c2;
        #pragma unroll 4
        for (int k = 0; k < 128; ++k) {
            float2 wk = *(const float2*)wrow;
            wrow += 128;
            #pragma unroll
            for (int i = 0; i < 4; ++i) {
                float a = s_hid[rbase + i][k0 + k];
                acc2[i][0] += a * wk.x;
                acc2[i][1] += a * wk.y;
            }
        }
    }
    __syncthreads();
    if (kh == 1) {
        #pragma unroll
        for (int i = 0; i < 4; ++i) {
            float2 o = { acc2[i][0], acc2[i][1] };
            *(float2*)&s_p2[rbase + i][c2] = o;
        }
    }
    __syncthreads();
    if (kh == 0) {
        float b0 = bf2[c2], b1 = bf2[c2 + 1];
        #pragma unroll
        for (int i = 0; i < 4; ++i) {
            float2 p = *(float2*)&s_p2[rbase + i][c2];
            float2 o = { acc2[i][0] + p.x + b0, acc2[i][1] + p.y + b1 };
            *(float2*)&fused[(size_t)(nbase + rbase + i) * HH + c2] = o;
        }
    }
}

// ---------------------------------------------------------------------------
// PROBE kernel: fusion v3 (FR=8, grid 512) — isolate the suspected regression.
// ---------------------------------------------------------------------------
#define F3 8
template<int REPS>
__global__ __launch_bounds__(512) void k_fusion3(
    const float* __restrict__ h2, const float* __restrict__ attn_ws,
    const float* __restrict__ wf1, const float* __restrict__ bf1,
    const float* __restrict__ wf2, const float* __restrict__ bf2,
    float* __restrict__ fused)
{
    __shared__ float s_in[F3][S1];
    __shared__ float s_hid[F3][S2];
    float (*s_part)[S2] = (float (*)[S2])&s_in[0][0];
    float (*s_p2)[S3]   = (float (*)[S3])&s_in[0][0];

    int nbase = blockIdx.x * F3;
    int wv   = threadIdx.x >> 6;
    int lane = threadIdx.x & 63;
    for (int rep = 0; rep < REPS; ++rep) {
        float at[VV];
        #pragma unroll
        for (int v = 0; v < VV; ++v) at[v] = attn_ws[v];
        for (int idx = threadIdx.x; idx < F3 * 128; idx += 512) {
            int r  = idx >> 7;
            int c4 = idx & 127;
            int v  = c4 >> 5;
            int h4 = c4 & 31;
            const float4* srcr = (const float4*)(h2 + ((size_t)v * NN + nbase + r) * HH);
            float4 x = srcr[h4];
            float s = at[v];
            x.x *= s; x.y *= s; x.z *= s; x.w *= s;
            *(float4*)&s_in[r][c4 * 4] = x;
        }
        __syncthreads();

        int cg = wv & 3, kh = wv >> 2;
        int ccol  = cg * 64 + (lane & 15) * 4;
        int rbase = (lane >> 4) * 2;
        float acc[2][4];
        #pragma unroll
        for (int i = 0; i < 2; ++i)
            #pragma unroll
            for (int j = 0; j < 4; ++j) acc[i][j] = 0.f;
        {
            int k0 = kh * 256;
            const float* wrow = wf1 + (size_t)k0 * 256 + ccol;
            #pragma unroll 4
            for (int k = 0; k < 256; ++k) {
                float4 wk = *(const float4*)wrow;
                wrow += 256;
                float a0 = s_in[rbase + 0][k0 + k];
                float a1 = s_in[rbase + 1][k0 + k];
                acc[0][0] += a0 * wk.x; acc[0][1] += a0 * wk.y; acc[0][2] += a0 * wk.z; acc[0][3] += a0 * wk.w;
                acc[1][0] += a1 * wk.x; acc[1][1] += a1 * wk.y; acc[1][2] += a1 * wk.z; acc[1][3] += a1 * wk.w;
            }
        }
        __syncthreads();
        if (kh == 1) {
            #pragma unroll
            for (int i = 0; i < 2; ++i)
                *(float4*)&s_part[rbase + i][ccol] = *(float4*)&acc[i][0];
        }
        __syncthreads();
        if (kh == 0) {
            float4 b = *(const float4*)&bf1[ccol];
            #pragma unroll
            for (int i = 0; i < 2; ++i) {
                float4 p = *(float4*)&s_part[rbase + i][ccol];
                float h0  = acc[i][0] + p.x + b.x;
                float h1v = acc[i][1] + p.y + b.y;
                float h2v = acc[i][2] + p.z + b.z;
                float h3  = acc[i][3] + p.w + b.w;
                float4 o;
                o.x = h0  > 0.f ? h0  : 0.f;
                o.y = h1v > 0.f ? h1v : 0.f;
                o.z = h2v > 0.f ? h2v : 0.f;
                o.w = h3  > 0.f ? h3  : 0.f;
                *(float4*)&s_hid[rbase + i][ccol] = o;
            }
        }
        __syncthreads();

        int c2 = cg * 32 + (lane & 15) * 2;
        float acc2[2][2];
        #pragma unroll
        for (int i = 0; i < 2; ++i) { acc2[i][0] = 0.f; acc2[i][1] = 0.f; }
        {
            int k0 = kh * 128;
            const float* wrow = wf2 + (size_t)k0 * 128 + c2;
            #pragma unroll 4
            for (int k = 0; k < 128; ++k) {
                float2 wk = *(const float2*)wrow;
                wrow += 128;
                #pragma unroll
                for (int i = 0; i < 2; ++i) {
                    float a = s_hid[rbase + i][k0 + k];
                    acc2[i][0] += a * wk.x;
                    acc2[i][1] += a * wk.y;
                }
            }
        }
        __syncthreads();
        if (kh == 1) {
            #pragma unroll
            for (int i = 0; i < 2; ++i) {
                float2 o = { acc2[i][0], acc2[i][1] };
                *(float2*)&s_p2[rbase + i][c2] = o;
            }
        }
        __syncthreads();
        if (kh == 0) {
            float b0 = bf2[c2], b1 = bf2[c2 + 1];
            #pragma unroll
            for (int i = 0; i < 2; ++i) {
                float2 p = *(float2*)&s_p2[rbase + i][c2];
                float2 o = { acc2[i][0] + p.x + b0, acc2[i][1] + p.y + b1 };
                *(float2*)&fused[(size_t)(nbase + rbase + i) * HH + c2] = o;
            }
        }
        __syncthreads();
    }
}

// ---------------------------------------------------------------------------
// A/B ROUND: pipeline = split layer2 + fusion v2 (restored). One probe:
// fusion_v3 x16 -> isolates the suspected regression with its own counters.
// pipeline_portion = dur - probe_dur (arithmetic validated in R11).
// ---------------------------------------------------------------------------
extern "C" void kernel_launch(void* const* d_in, const int* in_sizes, int n_in,
                              void* d_out, int out_size, void* d_ws, size_t ws_size,
                              hipStream_t stream)
{
    const float* adjs = (const float*)d_in[0];
    const float* w1   = (const float*)d_in[1];
    const float* b1   = (const float*)d_in[2];
    const float* w2   = (const float*)d_in[3];
    const float* b2   = (const float*)d_in[4];
    const float* wa1  = (const float*)d_in[5];
    const float* ba1  = (const float*)d_in[6];
    const float* wa2  = (const float*)d_in[7];
    const float* ba2  = (const float*)d_in[8];
    const float* wf1  = (const float*)d_in[9];
    const float* bf1  = (const float*)d_in[10];
    const float* wf2  = (const float*)d_in[11];
    const float* bf2  = (const float*)d_in[12];

    float* out   = (float*)d_out;
    float* fused = out;                        // [N, 128]
    float* attn  = out + (size_t)NN * HH;      // [V]
    float* h2    = attn + VV;                  // [V, N, H]

    char* w = (char*)d_ws;
    int*   nbr    = (int*)w;    w += (size_t)VV * NN * CAP * sizeof(int);
    int*   cnt    = (int*)w;    w += (size_t)VV * NN * sizeof(int);
    float* dinv   = (float*)w;  w += (size_t)VV * NN * sizeof(float);
    float* h1     = (float*)w;  w += (size_t)VV * NN * HH * sizeof(float);
    float* u      = (float*)w;  w += (size_t)VV * NN * HH * sizeof(float);
    float* part   = (float*)w;  w += (size_t)VV * CHP * HH * sizeof(float);
    float* attnws = (float*)w;  w += 256;
    float* fused_s = (float*)w; w += (size_t)NN * HH * sizeof(float);

    // ---- pipeline ----
    k_build_csr<<<VV * NN / 4, 256, 0, stream>>>(adjs, nbr, cnt, dinv);
    k_spmm1<<<VV * NN / 4, 512, 0, stream>>>(w1, b1, nbr, cnt, dinv, h1);
    k_gather2<<<VV * NN / 4, 512, 0, stream>>>(h1, nbr, cnt, dinv, u);
    k_gemm2c<<<VV * NN / GR, 256, 0, stream>>>(u, w2, b2, h2, part);
    k_attn<<<1, 512, 0, stream>>>(part, wa1, ba1, wa2, ba2, attn, attnws);
    k_fusion2<<<NN / F2, 512, 0, stream>>>(h2, attnws, wf1, bf1, wf2, bf2, fused);

    // ---- probe: fusion v3 isolated ----
    k_fusion3<16><<<NN / F3, 512, 0, stream>>>(h2, attnws, wf1, bf1, wf2, bf2, fused_s);
}

// Round 14
// 128.937 us; speedup vs baseline: 6.4170x; 6.4170x over previous
//
#include <hip/hip_runtime.h>

#define VV 4
#define NN 4096
#define HH 128
#define CAP 64
#define GR 32            // rows per block in gemm2c
#define CHP (NN / GR)    // 128 column-sum partial chunks per view
#define FV 16            // rows per block in fusion v5

typedef __attribute__((ext_vector_type(4))) float fvec4;   // nontemporal-loadable

// ---------------------------------------------------------------------------
// Kernel 1: scan dense adjacency -> per-row neighbor lists + dinv.
// (measured: HBM-floor bound, ~6.9 TB/s effective — done)
// ---------------------------------------------------------------------------
__global__ __launch_bounds__(256) void k_build_csr(
    const float* __restrict__ adjs, int* __restrict__ nbr,
    int* __restrict__ cnt, float* __restrict__ dinv)
{
    int wave = threadIdx.x >> 6;
    int lane = threadIdx.x & 63;
    int r = blockIdx.x * 4 + wave;              // global row in [0, V*N)
    const fvec4* row = (const fvec4*)(adjs + (size_t)r * NN);
    int* out = nbr + (size_t)r * CAP;
    unsigned long long lm = (1ull << lane) - 1ull;
    int base = 0;
    #pragma unroll 4
    for (int c = 0; c < NN / 256; ++c) {
        fvec4 x = __builtin_nontemporal_load(&row[c * 64 + lane]);
        int c0 = (x.x != 0.f), c1 = (x.y != 0.f), c2 = (x.z != 0.f), c3 = (x.w != 0.f);
        unsigned long long b0 = __ballot(c0), b1 = __ballot(c1);
        unsigned long long b2 = __ballot(c2), b3 = __ballot(c3);
        int pos = base + __popcll(b0 & lm) + __popcll(b1 & lm)
                       + __popcll(b2 & lm) + __popcll(b3 & lm);
        int e = c * 256 + lane * 4;
        if (c0 && pos < CAP) out[pos] = e;     pos += c0;
        if (c1 && pos < CAP) out[pos] = e + 1; pos += c1;
        if (c2 && pos < CAP) out[pos] = e + 2; pos += c2;
        if (c3 && pos < CAP) out[pos] = e + 3; pos += c3;
        base += __popcll(b0) + __popcll(b1) + __popcll(b2) + __popcll(b3);
    }
    if (lane == 0) {
        cnt[r]  = base < CAP ? base : CAP;
        dinv[r] = rsqrtf((float)(base + 1));   // +1 self loop
    }
}

// ---------------------------------------------------------------------------
// Kernel 2: h1 = relu(A_norm @ w1 + b1). 4 rows per 512-thread block.
// (measured 4.1 us)
// ---------------------------------------------------------------------------
__global__ __launch_bounds__(512) void k_spmm1(
    const float* __restrict__ w1, const float* __restrict__ b1,
    const int* __restrict__ nbr, const int* __restrict__ cnt,
    const float* __restrict__ dinv, float* __restrict__ h1)
{
    int xcd  = blockIdx.x & 7;
    int slot = blockIdx.x >> 3;
    int wid  = (xcd >> 1) * 1024 + slot * 2 + (xcd & 1);
    int g = threadIdx.x >> 7;
    int h = threadIdx.x & 127;
    int r = wid * 4 + g;
    int v = r >> 12;
    __shared__ int   s_j[4][CAP];
    __shared__ float s_w[4][CAP];
    int n = cnt[r];
    float dr = dinv[r];
    if (h < n) {
        int j = nbr[(size_t)r * CAP + h];
        s_j[g][h] = j;
        s_w[g][h] = dinv[v * NN + j];
    }
    __syncthreads();
    float acc = dr * w1[(size_t)r * HH + h];
    #pragma unroll 4
    for (int k = 0; k < n; ++k)
        acc += s_w[g][k] * w1[((size_t)(v * NN + s_j[g][k])) * HH + h];
    float val = dr * acc + b1[v * HH + h];
    h1[(size_t)r * HH + h] = val > 0.f ? val : 0.f;
}

// ---------------------------------------------------------------------------
// Kernel 3a: u = A_norm @ h1 (gather only; spmm1 clone).
// ---------------------------------------------------------------------------
__global__ __launch_bounds__(512) void k_gather2(
    const float* __restrict__ h1, const int* __restrict__ nbr,
    const int* __restrict__ cnt, const float* __restrict__ dinv,
    float* __restrict__ u)
{
    int xcd  = blockIdx.x & 7;
    int slot = blockIdx.x >> 3;
    int wid  = (xcd >> 1) * 1024 + slot * 2 + (xcd & 1);
    int g = threadIdx.x >> 7;
    int h = threadIdx.x & 127;
    int r = wid * 4 + g;
    int v = r >> 12;
    __shared__ int   s_j[4][CAP];
    __shared__ float s_w[4][CAP];
    int n = cnt[r];
    float dr = dinv[r];
    if (h < n) {
        int j = nbr[(size_t)r * CAP + h];
        s_j[g][h] = j;
        s_w[g][h] = dinv[v * NN + j];
    }
    __syncthreads();
    float acc = dr * h1[(size_t)r * HH + h];
    #pragma unroll 4
    for (int k = 0; k < n; ++k)
        acc += s_w[g][k] * h1[((size_t)(v * NN + s_j[g][k])) * HH + h];
    u[(size_t)r * HH + h] = dr * acc;
}

// ---------------------------------------------------------------------------
// Kernel 3b: h2 = relu(u @ w2 + b2) + per-block column partial sums.
// 32 rows/block, 256 threads, 4x4 register tile.
// ---------------------------------------------------------------------------
__global__ __launch_bounds__(256) void k_gemm2c(
    const float* __restrict__ u, const float* __restrict__ w2,
    const float* __restrict__ b2, float* __restrict__ h2,
    float* __restrict__ part)
{
    const int bpv = NN / GR;            // 128
    int v = blockIdx.x / bpv;
    int rbase_g = blockIdx.x * GR;      // first global row
    __shared__ float s_u[GR][HH];       // 16 KB
    __shared__ float s_p[8][HH];        // 4 KB
    const float4* src = (const float4*)(u + (size_t)rbase_g * HH);
    for (int idx = threadIdx.x; idx < GR * HH / 4; idx += 256)
        ((float4*)s_u)[idx] = src[idx];
    __syncthreads();

    int r0 = (threadIdx.x >> 5) * 4;          // 0..28
    int c0 = (threadIdx.x & 31) * 4;          // 0..124
    const float* wv = w2 + (size_t)v * HH * HH;
    float acc[4][4];
    #pragma unroll
    for (int i = 0; i < 4; ++i)
        #pragma unroll
        for (int j = 0; j < 4; ++j) acc[i][j] = 0.f;
    for (int k = 0; k < HH; k += 4) {
        float4 a[4], w[4];
        #pragma unroll
        for (int i = 0; i < 4; ++i) a[i] = *(const float4*)&s_u[r0 + i][k];
        #pragma unroll
        for (int kk = 0; kk < 4; ++kk) w[kk] = *(const float4*)&wv[(size_t)(k + kk) * HH + c0];
        #pragma unroll
        for (int i = 0; i < 4; ++i)
            #pragma unroll
            for (int j = 0; j < 4; ++j) {
                acc[i][j] += a[i].x * ((const float*)&w[0])[j];
                acc[i][j] += a[i].y * ((const float*)&w[1])[j];
                acc[i][j] += a[i].z * ((const float*)&w[2])[j];
                acc[i][j] += a[i].w * ((const float*)&w[3])[j];
            }
    }
    float p[4];
    #pragma unroll
    for (int j = 0; j < 4; ++j) {
        float b = b2[v * HH + c0 + j];
        float s = 0.f;
        #pragma unroll
        for (int i = 0; i < 4; ++i) {
            float val = acc[i][j] + b;
            val = val > 0.f ? val : 0.f;
            acc[i][j] = val;
            s += val;
        }
        p[j] = s;
    }
    float* dst = h2 + (size_t)rbase_g * HH;
    #pragma unroll
    for (int i = 0; i < 4; ++i) {
        float4 o = { acc[i][0], acc[i][1], acc[i][2], acc[i][3] };
        *(float4*)&dst[(size_t)(r0 + i) * HH + c0] = o;
    }
    *(float4*)&s_p[threadIdx.x >> 5][c0] = *(float4*)p;
    __syncthreads();
    if (threadIdx.x < HH) {
        float a = 0.f;
        #pragma unroll
        for (int q = 0; q < 8; ++q) a += s_p[q][threadIdx.x];
        part[(size_t)blockIdx.x * HH + threadIdx.x] = a;
    }
}

// ---------------------------------------------------------------------------
// Kernel 4: finish summaries, attention MLP, softmax. Single block (512 thr).
// ---------------------------------------------------------------------------
__global__ __launch_bounds__(512) void k_attn(
    const float* __restrict__ part, const float* __restrict__ wa1,
    const float* __restrict__ ba1, const float* __restrict__ wa2,
    const float* __restrict__ ba2, float* __restrict__ attn_out,
    float* __restrict__ attn_ws)
{
    __shared__ float s_sum[VV * HH];
    __shared__ float s_red[256];
    __shared__ float s_score[VV];
    {
        int v = threadIdx.x >> 7, h = threadIdx.x & 127;
        float a = 0.f;
        #pragma unroll 8
        for (int c = 0; c < CHP; ++c) a += part[(size_t)(v * CHP + c) * HH + h];
        s_sum[v * HH + h] = a * (1.0f / NN);
    }
    __syncthreads();
    if (threadIdx.x < 256) {
        int v = threadIdx.x >> 6, u = threadIdx.x & 63;
        float a = ba1[u];
        for (int k = 0; k < HH; ++k) a += s_sum[v * HH + k] * wa1[k * 64 + u];
        s_red[threadIdx.x] = tanhf(a) * wa2[u];
    }
    __syncthreads();
    if (threadIdx.x < VV) {
        float sc = ba2[0];
        for (int uu = 0; uu < 64; ++uu) sc += s_red[threadIdx.x * 64 + uu];
        s_score[threadIdx.x] = sc;
    }
    __syncthreads();
    if (threadIdx.x == 0) {
        float m = s_score[0];
        for (int i = 1; i < VV; ++i) m = fmaxf(m, s_score[i]);
        float e[VV], den = 0.f;
        for (int i = 0; i < VV; ++i) { e[i] = __expf(s_score[i] - m); den += e[i]; }
        for (int i = 0; i < VV; ++i) {
            float av = e[i] / den;
            attn_out[i] = av;
            attn_ws[i]  = av;
        }
    }
}

// ---------------------------------------------------------------------------
// Kernel 5: fusion MLP v5. FV=16 rows/block, 512 threads, grid 256.
// GEMM1: lane owns 4 UNIQUE cols (64 lanes x float4 = 256 cols, zero
// redundant loads); wave = (row-half, k-slice of 4); s_in via LDS broadcast.
// FMA:VMEM = 32:1 per wave (v2 was 16:1 with 4x redundancy; v3 was 8:1).
// Partials combined through 64 KB LDS (contiguous b128, conflict-free).
// ---------------------------------------------------------------------------
__global__ __launch_bounds__(512) void k_fusion5(
    const float* __restrict__ h2, const float* __restrict__ attn_ws,
    const float* __restrict__ wf1, const float* __restrict__ bf1,
    const float* __restrict__ wf2, const float* __restrict__ bf2,
    float* __restrict__ fused)
{
    __shared__ float s_in[FV][516];          // 33 KB
    __shared__ float s_pt[4][FV][256];       // 64 KB (GEMM1 partials; aliased below)
    __shared__ float s_hid[FV][260];         // 16.6 KB
    float (*s_p2)[FV][128] = (float (*)[FV][128])&s_pt[0][0][0];   // GEMM2 partials

    int nbase = blockIdx.x * FV;
    int wv   = threadIdx.x >> 6;
    int lane = threadIdx.x & 63;
    int rh = wv & 1;                 // row half: rows rh*8 .. rh*8+7
    int ks = wv >> 1;                // k-slice 0..3

    float at[VV];
    #pragma unroll
    for (int v = 0; v < VV; ++v) at[v] = attn_ws[v];

    // ---- stage fusion_in (attn-scaled) ----
    for (int idx = threadIdx.x; idx < FV * 128; idx += 512) {
        int r = idx >> 7, c4 = idx & 127, v = c4 >> 5, h4 = c4 & 31;
        const float4* srcr = (const float4*)(h2 + ((size_t)v * NN + nbase + r) * HH);
        float4 x = srcr[h4];
        float s = at[v];
        x.x *= s; x.y *= s; x.z *= s; x.w *= s;
        *(float4*)&s_in[r][c4 * 4] = x;
    }
    __syncthreads();

    // ---- GEMM1 partials: rows [rh*8,+8) x cols [lane*4,+4), k [ks*128,+128)
    {
        int col = lane * 4;
        int r0  = rh * 8;
        int k0  = ks * 128;
        float acc[8][4];
        #pragma unroll
        for (int i = 0; i < 8; ++i) { acc[i][0] = acc[i][1] = acc[i][2] = acc[i][3] = 0.f; }
        const float* wrow = wf1 + (size_t)k0 * 256 + col;
        for (int kk = 0; kk < 128; kk += 4) {
            float4 w0 = *(const float4*)(wrow);
            float4 w1 = *(const float4*)(wrow + 256);
            float4 w2 = *(const float4*)(wrow + 512);
            float4 w3 = *(const float4*)(wrow + 768);
            wrow += 1024;
            #pragma unroll
            for (int i = 0; i < 8; ++i) {
                float4 a = *(const float4*)&s_in[r0 + i][k0 + kk];   // broadcast
                acc[i][0] += a.x * w0.x + a.y * w1.x + a.z * w2.x + a.w * w3.x;
                acc[i][1] += a.x * w0.y + a.y * w1.y + a.z * w2.y + a.w * w3.y;
                acc[i][2] += a.x * w0.z + a.y * w1.z + a.z * w2.z + a.w * w3.z;
                acc[i][3] += a.x * w0.w + a.y * w1.w + a.z * w2.w + a.w * w3.w;
            }
        }
        #pragma unroll
        for (int i = 0; i < 8; ++i)
            *(float4*)&s_pt[ks][r0 + i][col] = *(float4*)&acc[i][0];
    }
    __syncthreads();

    // ---- combine1 + bias + relu -> s_hid (contiguous b128 reads) ----
    {
        int c0 = (threadIdx.x & 63) * 4;       // [0,256)
        int rr = threadIdx.x >> 6;             // [0,8)
        #pragma unroll
        for (int p = 0; p < 2; ++p) {
            int row = p * 8 + rr;
            float4 s0 = *(float4*)&s_pt[0][row][c0];
            float4 s1 = *(float4*)&s_pt[1][row][c0];
            float4 s2 = *(float4*)&s_pt[2][row][c0];
            float4 s3 = *(float4*)&s_pt[3][row][c0];
            float4 b  = *(const float4*)&bf1[c0];
            float4 o;
            o.x = s0.x + s1.x + s2.x + s3.x + b.x;
            o.y = s0.y + s1.y + s2.y + s3.y + b.y;
            o.z = s0.z + s1.z + s2.z + s3.z + b.z;
            o.w = s0.w + s1.w + s2.w + s3.w + b.w;
            o.x = o.x > 0.f ? o.x : 0.f;
            o.y = o.y > 0.f ? o.y : 0.f;
            o.z = o.z > 0.f ? o.z : 0.f;
            o.w = o.w > 0.f ? o.w : 0.f;
            *(float4*)&s_hid[row][c0] = o;
        }
    }
    __syncthreads();

    // ---- GEMM2 partials: rows [rh*8,+8) x cols [lane*2,+2), k [ks*64,+64)
    {
        int col = lane * 2;
        int r0  = rh * 8;
        int k0  = ks * 64;
        float acc[8][2];
        #pragma unroll
        for (int i = 0; i < 8; ++i) { acc[i][0] = 0.f; acc[i][1] = 0.f; }
        const float* wrow = wf2 + (size_t)k0 * 128 + col;
        for (int kk = 0; kk < 64; kk += 4) {
            float2 w0 = *(const float2*)(wrow);
            float2 w1 = *(const float2*)(wrow + 128);
            float2 w2 = *(const float2*)(wrow + 256);
            float2 w3 = *(const float2*)(wrow + 384);
            wrow += 512;
            #pragma unroll
            for (int i = 0; i < 8; ++i) {
                float4 a = *(const float4*)&s_hid[r0 + i][k0 + kk];  // broadcast
                acc[i][0] += a.x * w0.x + a.y * w1.x + a.z * w2.x + a.w * w3.x;
                acc[i][1] += a.x * w0.y + a.y * w1.y + a.z * w2.y + a.w * w3.y;
            }
        }
        #pragma unroll
        for (int i = 0; i < 8; ++i)
            *(float2*)&s_p2[ks][r0 + i][col] = *(float2*)&acc[i][0];
    }
    __syncthreads();

    // ---- combine2 + bias -> global ----
    {
        int c0  = (threadIdx.x & 31) * 4;      // [0,128)
        int row = threadIdx.x >> 5;            // [0,16)
        float4 s0 = *(float4*)&s_p2[0][row][c0];
        float4 s1 = *(float4*)&s_p2[1][row][c0];
        float4 s2 = *(float4*)&s_p2[2][row][c0];
        float4 s3 = *(float4*)&s_p2[3][row][c0];
        float4 b  = *(const float4*)&bf2[c0];
        float4 o;
        o.x = s0.x + s1.x + s2.x + s3.x + b.x;
        o.y = s0.y + s1.y + s2.y + s3.y + b.y;
        o.z = s0.z + s1.z + s2.z + s3.z + b.z;
        o.w = s0.w + s1.w + s2.w + s3.w + b.w;
        *(float4*)&fused[(size_t)(nbase + row) * HH + c0] = o;
    }
}

// ---------------------------------------------------------------------------
// CLEAN ROUND: split layer2 + fusion v5. No probes.
// ---------------------------------------------------------------------------
extern "C" void kernel_launch(void* const* d_in, const int* in_sizes, int n_in,
                              void* d_out, int out_size, void* d_ws, size_t ws_size,
                              hipStream_t stream)
{
    const float* adjs = (const float*)d_in[0];
    const float* w1   = (const float*)d_in[1];
    const float* b1   = (const float*)d_in[2];
    const float* w2   = (const float*)d_in[3];
    const float* b2   = (const float*)d_in[4];
    const float* wa1  = (const float*)d_in[5];
    const float* ba1  = (const float*)d_in[6];
    const float* wa2  = (const float*)d_in[7];
    const float* ba2  = (const float*)d_in[8];
    const float* wf1  = (const float*)d_in[9];
    const float* bf1  = (const float*)d_in[10];
    const float* wf2  = (const float*)d_in[11];
    const float* bf2  = (const float*)d_in[12];

    float* out   = (float*)d_out;
    float* fused = out;                        // [N, 128]
    float* attn  = out + (size_t)NN * HH;      // [V]
    float* h2    = attn + VV;                  // [V, N, H]

    char* w = (char*)d_ws;
    int*   nbr    = (int*)w;    w += (size_t)VV * NN * CAP * sizeof(int);
    int*   cnt    = (int*)w;    w += (size_t)VV * NN * sizeof(int);
    float* dinv   = (float*)w;  w += (size_t)VV * NN * sizeof(float);
    float* h1     = (float*)w;  w += (size_t)VV * NN * HH * sizeof(float);
    float* u      = (float*)w;  w += (size_t)VV * NN * HH * sizeof(float);
    float* part   = (float*)w;  w += (size_t)VV * CHP * HH * sizeof(float);
    float* attnws = (float*)w;  w += 256;

    k_build_csr<<<VV * NN / 4, 256, 0, stream>>>(adjs, nbr, cnt, dinv);
    k_spmm1<<<VV * NN / 4, 512, 0, stream>>>(w1, b1, nbr, cnt, dinv, h1);
    k_gather2<<<VV * NN / 4, 512, 0, stream>>>(h1, nbr, cnt, dinv, u);
    k_gemm2c<<<VV * NN / GR, 256, 0, stream>>>(u, w2, b2, h2, part);
    k_attn<<<1, 512, 0, stream>>>(part, wa1, ba1, wa2, ba2, attn, attnws);
    k_fusion5<<<NN / FV, 512, 0, stream>>>(h2, attnws, wf1, bf1, wf2, bf2, fused);
}